// Round 7
// baseline (320.070 us; speedup 1.0000x reference)
//
#include <hip/hip_runtime.h>
#include <hip/hip_cooperative_groups.h>
#include <stdint.h>

// KANLinear fused kernel v6 for MI355X (gfx950).
// out = x @ bw + scaling * einsum('bik,iok->bo', basis(x), sw)
// One bf16 MFMA GEMM: K = 256 i-slabs x 80 (66 basis + base at k=66 + zero pad).
// v6 changes vs v5 (98.8us main; per-phase barrier overhead dominated: 64 tiny
// phases/CU; 3-serial-shfl chain in BASIS; ~65us of launch gaps outside main):
//   - 2-slab phases: 16 barriers (was 33), 20 MFMA + 2 independent BASIS per
//     phase. A LDS [2][2][BM*APAD] = 45KB (2 blocks/CU keeps 90KB < 160KB).
//   - window-sum via 2 PARALLEL ds_bpermute (1 LDS latency) instead of 3
//     serial shfl_xor (3 latencies).
//   - ONE cooperative launch {pack | grid.sync | main | grid.sync | reduce}
//     with runtime fallback to 3 separate launches. Bodies are the verified
//     v5 kernels verbatim (pack) / restructured main / same reduce.

#define IN_F 256
#define OUT_F 256
#define NB 66
#define KP 80
#define APAD 88      // A LDS row stride in ushorts
#define KSPLIT 8
#define SLABS 32     // IN_F / KSPLIT
#define PAIRS 16
#define BM 64
#define NTHREADS 512
#define GRID_MAIN 512   // (4096/BM) * KSPLIT

typedef __attribute__((ext_vector_type(8))) short bf16x8;
typedef __attribute__((ext_vector_type(16))) float f32x16;

namespace cg = cooperative_groups;

__device__ __forceinline__ unsigned int cvtpk(float lo, float hi) {
  unsigned int r;
  asm("v_cvt_pk_bf16_f32 %0, %1, %2" : "=v"(r) : "v"(lo), "v"(hi));
  return r;   // [15:0]=bf16(lo), [31:16]=bf16(hi), RNE
}

// ---- pack W' -> wp2, layout [i][half][lane 0..255][kk 0..4][8 bf16] ----
// k<66 = sw*scaling[o]; k=66 = bw; 67..79 = 0. Scaling mean fused (sca col-sum).
__device__ __forceinline__ void pack_body(int i, int o,
    const float* __restrict__ sw, const float* __restrict__ bw,
    const float* __restrict__ sca, unsigned short* __restrict__ wp2) {
  float sc = 0.0f;
  #pragma unroll 8
  for (int ii = 0; ii < IN_F; ii++)
    sc += fmaxf(sca[(size_t)ii * OUT_F + o], 1e-7f);
  sc *= (1.0f / 256.0f);
  const float2* src = (const float2*)(sw + ((size_t)i * OUT_F + o) * NB);
  float v[80];
  #pragma unroll
  for (int j = 0; j < 33; j++) {
    float2 t2 = src[j];
    v[2 * j] = t2.x * sc;
    v[2 * j + 1] = t2.y * sc;
  }
  v[66] = bw[(size_t)i * OUT_F + o];
  #pragma unroll
  for (int k = 67; k < 80; k++) v[k] = 0.0f;
  uint4* dst = (uint4*)wp2;
  #pragma unroll
  for (int half = 0; half < 2; half++) {
    #pragma unroll
    for (int kk = 0; kk < 5; kk++) {
      const float* p = v + kk * 16 + half * 8;
      uint4 u;
      unsigned int* up = (unsigned int*)&u;
      #pragma unroll
      for (int h = 0; h < 4; h++) up[h] = cvtpk(p[2 * h], p[2 * h + 1]);
      dst[(((size_t)i * 2 + half) * 256 + o) * 5 + kk] = u;
    }
  }
}

__global__ void kan_pack(const float* __restrict__ sw, const float* __restrict__ bw,
                         const float* __restrict__ sca, unsigned short* __restrict__ wp2) {
  pack_body(blockIdx.x, threadIdx.x, sw, bw, sca, wp2);
}

// ---- main fused GEMM body (2-slab phases) ----
__device__ __forceinline__ void main_body(const float* __restrict__ x,
    const unsigned short* __restrict__ wp2, float* __restrict__ dst,
    int atomic_mode) {
  __shared__ unsigned short A[2][2][BM * APAD];   // 45056 B

  const int t = threadIdx.x;
  const int lane = t & 63;
  const int w = t >> 6;            // 0..7: wave N-col (32 cols each)
  const int ml = lane & 31;
  const int half = lane >> 5;
  const int mblk = (int)blockIdx.x >> 3;
  const int kidx = (int)blockIdx.x & 7;   // XCD-affine split-K index
  const int b0 = mblk * BM;
  const int ibase = kidx * SLABS;

  // basis thread mapping: row rb = t>>3, 8 threads/row; q<3 = exp threads
  const int rb = t >> 3;           // 0..63
  const int q = t & 7;
  // bpermute addresses for the 3-exp-lane window sum (parallel, 1 LDS latency)
  int qa = q + 1; if (qa > 2) qa -= 3;
  int qb = q + 2; if (qb > 2) qb -= 3;
  const int adA = ((lane & ~7) + qa) << 2;
  const int adB = ((lane & ~7) + qb) << 2;

  const float* xrow = x + (size_t)(b0 + rb) * IN_F;
  // B: [i][half][lanecol][kk][8]; per-slab stride 2*256*40 = 20480 ushorts
  const unsigned short* bptr =
      wp2 + (((size_t)ibase * 2 + half) * 256 + (w * 32 + ml)) * 40;

  bf16x8 bregA[5], bregB[5];
  f32x16 acc[2] = {f32x16{}, f32x16{}};

#define LOADBA()                                                               \
  {                                                                            \
    _Pragma("unroll") for (int kk = 0; kk < 5; kk++)                           \
      bregA[kk] = *(const bf16x8*)(bptr + kk * 8);                             \
    bptr += 20480;                                                             \
  }
#define LOADBB()                                                               \
  {                                                                            \
    _Pragma("unroll") for (int kk = 0; kk < 5; kk++)                           \
      bregB[kk] = *(const bf16x8*)(bptr + kk * 8);                             \
    bptr += 20480;                                                             \
  }

// Windowed basis: ikc = clamp(round(65*tl),0,65); groups g0..g0+2 of 8 slots
// cover [ikc-8, ikc+8]. Excluded slots: e <= e^-41.8 -> bv <= 1e-11. Zero
// groups: zq=q-3 -> zg = zq<g0 ? zq : zq+3 (q=3,4 also take zq+5). Slot 66 = x.
#define BASIS(PB, SS, XVAL)                                                    \
  {                                                                            \
    const float xr_ = (XVAL);                                                  \
    const float xc_ = fminf(fmaxf(xr_, -1.0f), 1.0f);                          \
    const float xs_ = (xc_ + 1.0f) * (63.0f / (2.0f + 1e-7f));                 \
    const float tl_ = xs_ - fminf(floorf(xs_), 61.0f);                         \
    const int ikc_ = min((int)(tl_ * 65.0f + 0.5f), 65);                       \
    const int g0_ = max((ikc_ - 8) >> 3, 0);                                   \
    unsigned short* Arow_ = &A[PB][SS][rb * APAD];                             \
    const int kbase_ = (g0_ + q) * 8;                                          \
    float e_[8];                                                               \
    float s_ = 0.0f;                                                           \
    if (q < 3) {                                                               \
      const float tb_ = tl_ - (float)kbase_ * (1.0f / 65.0f);                  \
      _Pragma("unroll") for (int j = 0; j < 8; j++) {                          \
        const float d_ = tb_ - (float)j * (1.0f / 65.0f);                      \
        float ee = __builtin_amdgcn_exp2f(-3142.1892f * d_ * d_);              \
        ee = (kbase_ + j < 66) ? ee : 0.0f;                                    \
        e_[j] = ee;                                                            \
        s_ += ee;                                                              \
      }                                                                        \
    }                                                                          \
    const float sa_ = __uint_as_float(                                         \
        (unsigned)__builtin_amdgcn_ds_bpermute(adA, (int)__float_as_uint(s_)));\
    const float sb_ = __uint_as_float(                                         \
        (unsigned)__builtin_amdgcn_ds_bpermute(adB, (int)__float_as_uint(s_)));\
    const float r_ = __fdividef(1.0f, s_ + sa_ + sb_ + 1e-7f);                 \
    if (q < 3) {                                                               \
      uint4 u_;                                                                \
      unsigned int* up_ = (unsigned int*)&u_;                                  \
      _Pragma("unroll") for (int h = 0; h < 4; h++) {                          \
        float f0 = e_[2 * h] * r_;                                             \
        const float f1 = e_[2 * h + 1] * r_;                                   \
        f0 = (kbase_ + 2 * h == 66) ? xr_ : f0;                                \
        up_[h] = cvtpk(f0, f1);                                                \
      }                                                                        \
      *(uint4*)(Arow_ + kbase_) = u_;                                          \
    } else {                                                                   \
      const unsigned int bu_ = cvtpk(xr_, 0.0f);                               \
      const int zq_ = q - 3;                                                   \
      const int zg_ = (zq_ < g0_) ? zq_ : zq_ + 3;                             \
      uint4 z_ = {0u, 0u, 0u, 0u};                                             \
      uint4 b_ = {0u, bu_, 0u, 0u};   /* slot 66 = word1.lo of group 8 */      \
      *(uint4*)(Arow_ + zg_ * 8) = (zg_ == 8) ? b_ : z_;                       \
      if (zq_ < 2) {                                                           \
        const int zg2_ = (zq_ + 5 < g0_) ? zq_ + 5 : zq_ + 8;                  \
        *(uint4*)(Arow_ + zg2_ * 8) = (zg2_ == 8) ? b_ : z_;                   \
      }                                                                        \
    }                                                                          \
  }

#define MFMA_SLAB(PB, SS, BR)                                                  \
  {                                                                            \
    const unsigned short* Ac = &A[PB][SS][0];                                  \
    _Pragma("unroll") for (int kk = 0; kk < 5; kk++) {                         \
      const int ko = kk * 16 + half * 8;                                       \
      bf16x8 a0 = *(const bf16x8*)(Ac + ml * APAD + ko);                       \
      bf16x8 a1 = *(const bf16x8*)(Ac + (32 + ml) * APAD + ko);                \
      acc[0] = __builtin_amdgcn_mfma_f32_32x32x16_bf16(a0, BR[kk], acc[0], 0, 0, 0); \
      acc[1] = __builtin_amdgcn_mfma_f32_32x32x16_bf16(a1, BR[kk], acc[1], 0, 0, 0); \
    }                                                                          \
  }

  // ---- prologue: slabs 0,1 ----
  BASIS(0, 0, xrow[ibase]);
  BASIS(0, 1, xrow[ibase + 1]);
  LOADBA();
  LOADBB();
  float xn0 = xrow[ibase + 2];
  float xn1 = xrow[ibase + 3];
  __syncthreads();

  // ---- 16 two-slab phases ----
  for (int p = 0; p < PAIRS; p++) {
    MFMA_SLAB(p & 1, 0, bregA);
    if (p < PAIRS - 1) LOADBA();          // slab 2p+2 (WAR after MFMA issue)
    MFMA_SLAB(p & 1, 1, bregB);
    if (p < PAIRS - 1) LOADBB();          // slab 2p+3
    if (p < PAIRS - 1) {
      BASIS((p + 1) & 1, 0, xn0);
      BASIS((p + 1) & 1, 1, xn1);
      if (p < PAIRS - 2) {
        xn0 = xrow[ibase + 2 * p + 4];
        xn1 = xrow[ibase + 2 * p + 5];
      }
    }
    __syncthreads();
  }

  // ---- epilogue: C/D layout col=lane&31, row=(r&3)+8*(r>>2)+4*(lane>>5) ----
  const int colb = w * 32 + ml;
  if (atomic_mode) {
    #pragma unroll
    for (int mb = 0; mb < 2; mb++) {
      #pragma unroll
      for (int r = 0; r < 16; r++) {
        const int row = b0 + mb * 32 + (r & 3) + 8 * (r >> 2) + 4 * half;
        atomicAdd(&dst[(size_t)row * OUT_F + colb], acc[mb][r]);
      }
    }
  } else {
    float* pd = dst + (size_t)kidx * ((size_t)4096 * OUT_F);
    #pragma unroll
    for (int mb = 0; mb < 2; mb++) {
      #pragma unroll
      for (int r = 0; r < 16; r++) {
        const int row = b0 + mb * 32 + (r & 3) + 8 * (r >> 2) + 4 * half;
        pd[(size_t)row * OUT_F + colb] = acc[mb][r];
      }
    }
  }
#undef LOADBA
#undef LOADBB
#undef BASIS
#undef MFMA_SLAB
}

__global__ __launch_bounds__(NTHREADS, 4) void kan_main(
    const float* __restrict__ x, const unsigned short* __restrict__ wp2,
    float* __restrict__ dst, int atomic_mode) {
  main_body(x, wp2, dst, atomic_mode);
}

// ---- split-K reduce: out = sum of 8 partial tiles ----
__device__ __forceinline__ void reduce_body(size_t gid,
    const float* __restrict__ part, float* __restrict__ out) {
  const size_t j = gid * 4;
  float4 a = *(const float4*)(part + j);
  #pragma unroll
  for (int s = 1; s < 8; s++) {
    float4 b = *(const float4*)(part + (size_t)s * 1048576 + j);
    a.x += b.x; a.y += b.y; a.z += b.z; a.w += b.w;
  }
  *(float4*)(out + j) = a;
}

__global__ void kan_reduce(const float* __restrict__ part, float* __restrict__ out) {
  reduce_body((size_t)blockIdx.x * 256 + threadIdx.x, part, out);
}

// ---- fused cooperative kernel: pack | sync | main | sync | reduce ----
__global__ __launch_bounds__(NTHREADS, 4) void kan_coop(
    const float* __restrict__ x, const float* __restrict__ bw,
    const float* __restrict__ sw, const float* __restrict__ sca,
    unsigned short* __restrict__ wp2, float* __restrict__ part,
    float* __restrict__ out) {
  if (blockIdx.x < 256 && threadIdx.x < 256)
    pack_body(blockIdx.x, threadIdx.x, sw, bw, sca, wp2);
  cg::this_grid().sync();
  main_body(x, wp2, part, 0);
  cg::this_grid().sync();
  reduce_body((size_t)blockIdx.x * NTHREADS + threadIdx.x, part, out);
}

// ---- naive fallback (only if d_ws is too small): correct, slow ----
__global__ void kan_naive(const float* __restrict__ x, const float* __restrict__ bw,
                          const float* __restrict__ sw, const float* __restrict__ sca,
                          float* __restrict__ out) {
  const int o = threadIdx.x;
  const int b = blockIdx.x;
  float accb = 0.0f, accs = 0.0f, scl = 0.0f;
  for (int i = 0; i < IN_F; i++) {
    const float xraw = x[(size_t)b * IN_F + i];
    accb += xraw * bw[(size_t)i * OUT_F + o];
    scl += fmaxf(sca[(size_t)i * OUT_F + o], 1e-7f);
    const float xc = fminf(fmaxf(xraw, -1.0f), 1.0f);
    const float xs = (xc + 1.0f) * (63.0f / (2.0f + 1e-7f));
    const float tl = xs - fminf(floorf(xs), 61.0f);
    const int kc = (int)(tl * 65.0f + 0.5f);
    const int k0 = max(0, min(kc - 8, 50));
    float e[16]; float s = 0.0f;
    #pragma unroll
    for (int j = 0; j < 16; j++) {
      float d = tl - (float)(k0 + j) * (1.0f / 65.0f);
      e[j] = __expf(-2178.0f * d * d);
      s += e[j];
    }
    const float r = __fdividef(1.0f, s + 1e-7f);
    const float* wrow = sw + ((size_t)i * OUT_F + o) * NB + k0;
    float dot = 0.0f;
    #pragma unroll
    for (int j = 0; j < 16; j++) dot += e[j] * wrow[j];
    accs += dot * r;
  }
  out[(size_t)b * OUT_F + o] = accb + accs * (scl * (1.0f / 256.0f));
}

extern "C" void kernel_launch(void* const* d_in, const int* in_sizes, int n_in,
                              void* d_out, int out_size, void* d_ws, size_t ws_size,
                              hipStream_t stream) {
  const float* x   = (const float*)d_in[0];
  const float* bw  = (const float*)d_in[1];
  const float* sw  = (const float*)d_in[2];
  const float* sca = (const float*)d_in[3];
  float* out = (float*)d_out;

  const size_t WP2_BYTES  = (size_t)IN_F * OUT_F * KP * 2;          // 10485760
  const size_t PART_BYTES = (size_t)KSPLIT * 4096 * OUT_F * 4;      // 33554432

  if (ws_size >= WP2_BYTES + PART_BYTES) {
    unsigned short* wp2 = (unsigned short*)d_ws;
    float* part = (float*)((char*)d_ws + WP2_BYTES);
    // try single cooperative launch; fall back to 3 launches if rejected
    void* args[] = {(void*)&x, (void*)&bw, (void*)&sw, (void*)&sca,
                    (void*)&wp2, (void*)&part, (void*)&out};
    hipError_t e = hipLaunchCooperativeKernel(
        reinterpret_cast<const void*>(&kan_coop), dim3(GRID_MAIN),
        dim3(NTHREADS), args, 0, stream);
    if (e != hipSuccess) {
      kan_pack<<<256, 256, 0, stream>>>(sw, bw, sca, wp2);
      kan_main<<<GRID_MAIN, NTHREADS, 0, stream>>>(x, wp2, part, 0);
      kan_reduce<<<1024, 256, 0, stream>>>(part, out);
    }
  } else if (ws_size >= WP2_BYTES) {
    unsigned short* wp2 = (unsigned short*)d_ws;
    (void)hipMemsetAsync(d_out, 0, (size_t)out_size * sizeof(float), stream);
    kan_pack<<<256, 256, 0, stream>>>(sw, bw, sca, wp2);
    kan_main<<<GRID_MAIN, NTHREADS, 0, stream>>>(x, wp2, out, 1);
  } else {
    kan_naive<<<4096, 256, 0, stream>>>(x, bw, sw, sca, out);
  }
}

// Round 8
// 181.387 us; speedup vs baseline: 1.7646x; 1.7646x over previous
//
#include <hip/hip_runtime.h>
#include <stdint.h>

// KANLinear fused kernel v7 for MI355X (gfx950).
// out = x @ bw + scaling * einsum('bik,iok->bo', basis(x), sw)
// One bf16 MFMA GEMM: K = 256 i-slabs x 80 (66 basis + base at k=66 + zero pad).
// v7 = v6's main (2-slab phases + parallel bpermute window-sum; validated
// end-to-end by the v6 coop run, absmax 0.03125) launched via the proven
// 3-kernel path. Coop deleted: it forced pack's float v[80] under main's
// (512,4) reg budget -> spills (VGPR 64, FETCH 11.5->37.5MB) and grid-sync
// convoys; kan_coop ran 246us vs v5 main's 99us.
//   - 2-slab phases: 16 barriers (was 33 in v5), 20 MFMA + 2 BASIS per phase.
//     A LDS [2][2][BM*APAD] = 45KB (2 blocks/CU -> 90KB < 160KB).
//   - window-sum: 2 parallel ds_bpermute (1 LDS latency) vs 3 serial shfl_xor.
//   - regs: bregA+bregB 40 + acc 32 + misc ~30 ~= 100 <= 128 @ (512,4).

#define IN_F 256
#define OUT_F 256
#define NB 66
#define KP 80
#define APAD 88      // A LDS row stride in ushorts
#define KSPLIT 8
#define SLABS 32     // IN_F / KSPLIT
#define PAIRS 16
#define BM 64
#define NTHREADS 512
#define GRID_MAIN 512   // (4096/BM) * KSPLIT

typedef __attribute__((ext_vector_type(8))) short bf16x8;
typedef __attribute__((ext_vector_type(16))) float f32x16;

__device__ __forceinline__ unsigned int cvtpk(float lo, float hi) {
  unsigned int r;
  asm("v_cvt_pk_bf16_f32 %0, %1, %2" : "=v"(r) : "v"(lo), "v"(hi));
  return r;   // [15:0]=bf16(lo), [31:16]=bf16(hi), RNE
}

// ---- pack W' -> wp2, layout [i][half][lane 0..255][kk 0..4][8 bf16] ----
// k<66 = sw*scaling[o]; k=66 = bw; 67..79 = 0. Scaling mean fused (sca col-sum).
__global__ void kan_pack(const float* __restrict__ sw, const float* __restrict__ bw,
                         const float* __restrict__ sca, unsigned short* __restrict__ wp2) {
  const int i = blockIdx.x, o = threadIdx.x;
  float sc = 0.0f;
  #pragma unroll 8
  for (int ii = 0; ii < IN_F; ii++)
    sc += fmaxf(sca[(size_t)ii * OUT_F + o], 1e-7f);
  sc *= (1.0f / 256.0f);
  const float2* src = (const float2*)(sw + ((size_t)i * OUT_F + o) * NB);
  float v[80];
  #pragma unroll
  for (int j = 0; j < 33; j++) {
    float2 t2 = src[j];
    v[2 * j] = t2.x * sc;
    v[2 * j + 1] = t2.y * sc;
  }
  v[66] = bw[(size_t)i * OUT_F + o];
  #pragma unroll
  for (int k = 67; k < 80; k++) v[k] = 0.0f;
  uint4* dst = (uint4*)wp2;
  #pragma unroll
  for (int half = 0; half < 2; half++) {
    #pragma unroll
    for (int kk = 0; kk < 5; kk++) {
      const float* p = v + kk * 16 + half * 8;
      uint4 u;
      unsigned int* up = (unsigned int*)&u;
      #pragma unroll
      for (int h = 0; h < 4; h++) up[h] = cvtpk(p[2 * h], p[2 * h + 1]);
      dst[(((size_t)i * 2 + half) * 256 + o) * 5 + kk] = u;
    }
  }
}

// ---- main fused GEMM (2-slab phases) ----
__global__ __launch_bounds__(NTHREADS, 4) void kan_main(
    const float* __restrict__ x, const unsigned short* __restrict__ wp2,
    float* __restrict__ dst, int atomic_mode) {
  __shared__ unsigned short A[2][2][BM * APAD];   // 45056 B

  const int t = threadIdx.x;
  const int lane = t & 63;
  const int w = t >> 6;            // 0..7: wave N-col (32 cols each)
  const int ml = lane & 31;
  const int half = lane >> 5;
  const int mblk = (int)blockIdx.x >> 3;
  const int kidx = (int)blockIdx.x & 7;   // XCD-affine split-K index
  const int b0 = mblk * BM;
  const int ibase = kidx * SLABS;

  // basis thread mapping: row rb = t>>3, 8 threads/row; q<3 = exp threads
  const int rb = t >> 3;           // 0..63
  const int q = t & 7;
  // bpermute addresses for the 3-exp-lane window sum (parallel, 1 LDS latency)
  int qa = q + 1; if (qa > 2) qa -= 3;
  int qb = q + 2; if (qb > 2) qb -= 3;
  const int adA = ((lane & ~7) + qa) << 2;
  const int adB = ((lane & ~7) + qb) << 2;

  const float* xrow = x + (size_t)(b0 + rb) * IN_F;
  // B: [i][half][lanecol][kk][8]; per-slab stride 2*256*40 = 20480 ushorts
  const unsigned short* bptr =
      wp2 + (((size_t)ibase * 2 + half) * 256 + (w * 32 + ml)) * 40;

  bf16x8 bregA[5], bregB[5];
  f32x16 acc[2] = {f32x16{}, f32x16{}};

#define LOADBA()                                                               \
  {                                                                            \
    _Pragma("unroll") for (int kk = 0; kk < 5; kk++)                           \
      bregA[kk] = *(const bf16x8*)(bptr + kk * 8);                             \
    bptr += 20480;                                                             \
  }
#define LOADBB()                                                               \
  {                                                                            \
    _Pragma("unroll") for (int kk = 0; kk < 5; kk++)                           \
      bregB[kk] = *(const bf16x8*)(bptr + kk * 8);                             \
    bptr += 20480;                                                             \
  }

// Windowed basis: ikc = clamp(round(65*tl),0,65); groups g0..g0+2 of 8 slots
// cover [ikc-8, ikc+8]. Excluded slots: e <= e^-41.8 -> bv <= 1e-11. Zero
// groups: zq=q-3 -> zg = zq<g0 ? zq : zq+3 (q=3,4 also take zq+5). Slot 66 = x.
#define BASIS(PB, SS, XVAL)                                                    \
  {                                                                            \
    const float xr_ = (XVAL);                                                  \
    const float xc_ = fminf(fmaxf(xr_, -1.0f), 1.0f);                          \
    const float xs_ = (xc_ + 1.0f) * (63.0f / (2.0f + 1e-7f));                 \
    const float tl_ = xs_ - fminf(floorf(xs_), 61.0f);                         \
    const int ikc_ = min((int)(tl_ * 65.0f + 0.5f), 65);                       \
    const int g0_ = max((ikc_ - 8) >> 3, 0);                                   \
    unsigned short* Arow_ = &A[PB][SS][rb * APAD];                             \
    const int kbase_ = (g0_ + q) * 8;                                          \
    float e_[8];                                                               \
    float s_ = 0.0f;                                                           \
    if (q < 3) {                                                               \
      const float tb_ = tl_ - (float)kbase_ * (1.0f / 65.0f);                  \
      _Pragma("unroll") for (int j = 0; j < 8; j++) {                          \
        const float d_ = tb_ - (float)j * (1.0f / 65.0f);                      \
        float ee = __builtin_amdgcn_exp2f(-3142.1892f * d_ * d_);              \
        ee = (kbase_ + j < 66) ? ee : 0.0f;                                    \
        e_[j] = ee;                                                            \
        s_ += ee;                                                              \
      }                                                                        \
    }                                                                          \
    const float sa_ = __uint_as_float(                                         \
        (unsigned)__builtin_amdgcn_ds_bpermute(adA, (int)__float_as_uint(s_)));\
    const float sb_ = __uint_as_float(                                         \
        (unsigned)__builtin_amdgcn_ds_bpermute(adB, (int)__float_as_uint(s_)));\
    const float r_ = __fdividef(1.0f, s_ + sa_ + sb_ + 1e-7f);                 \
    if (q < 3) {                                                               \
      uint4 u_;                                                                \
      unsigned int* up_ = (unsigned int*)&u_;                                  \
      _Pragma("unroll") for (int h = 0; h < 4; h++) {                          \
        float f0 = e_[2 * h] * r_;                                             \
        const float f1 = e_[2 * h + 1] * r_;                                   \
        f0 = (kbase_ + 2 * h == 66) ? xr_ : f0;                                \
        up_[h] = cvtpk(f0, f1);                                                \
      }                                                                        \
      *(uint4*)(Arow_ + kbase_) = u_;                                          \
    } else {                                                                   \
      const unsigned int bu_ = cvtpk(xr_, 0.0f);                               \
      const int zq_ = q - 3;                                                   \
      const int zg_ = (zq_ < g0_) ? zq_ : zq_ + 3;                             \
      uint4 z_ = {0u, 0u, 0u, 0u};                                             \
      uint4 b_ = {0u, bu_, 0u, 0u};   /* slot 66 = word1.lo of group 8 */      \
      *(uint4*)(Arow_ + zg_ * 8) = (zg_ == 8) ? b_ : z_;                       \
      if (zq_ < 2) {                                                           \
        const int zg2_ = (zq_ + 5 < g0_) ? zq_ + 5 : zq_ + 8;                  \
        *(uint4*)(Arow_ + zg2_ * 8) = (zg2_ == 8) ? b_ : z_;                   \
      }                                                                        \
    }                                                                          \
  }

#define MFMA_SLAB(PB, SS, BR)                                                  \
  {                                                                            \
    const unsigned short* Ac = &A[PB][SS][0];                                  \
    _Pragma("unroll") for (int kk = 0; kk < 5; kk++) {                         \
      const int ko = kk * 16 + half * 8;                                       \
      bf16x8 a0 = *(const bf16x8*)(Ac + ml * APAD + ko);                       \
      bf16x8 a1 = *(const bf16x8*)(Ac + (32 + ml) * APAD + ko);                \
      acc[0] = __builtin_amdgcn_mfma_f32_32x32x16_bf16(a0, BR[kk], acc[0], 0, 0, 0); \
      acc[1] = __builtin_amdgcn_mfma_f32_32x32x16_bf16(a1, BR[kk], acc[1], 0, 0, 0); \
    }                                                                          \
  }

  // ---- prologue: slabs 0,1 ----
  BASIS(0, 0, xrow[ibase]);
  BASIS(0, 1, xrow[ibase + 1]);
  LOADBA();
  LOADBB();
  float xn0 = xrow[ibase + 2];
  float xn1 = xrow[ibase + 3];
  __syncthreads();

  // ---- 16 two-slab phases ----
  for (int p = 0; p < PAIRS; p++) {
    MFMA_SLAB(p & 1, 0, bregA);
    if (p < PAIRS - 1) LOADBA();          // slab 2p+2 (WAR after MFMA issue)
    MFMA_SLAB(p & 1, 1, bregB);
    if (p < PAIRS - 1) LOADBB();          // slab 2p+3
    if (p < PAIRS - 1) {
      BASIS((p + 1) & 1, 0, xn0);
      BASIS((p + 1) & 1, 1, xn1);
      if (p < PAIRS - 2) {
        xn0 = xrow[ibase + 2 * p + 4];
        xn1 = xrow[ibase + 2 * p + 5];
      }
    }
    __syncthreads();
  }

  // ---- epilogue: C/D layout col=lane&31, row=(r&3)+8*(r>>2)+4*(lane>>5) ----
  const int colb = w * 32 + ml;
  if (atomic_mode) {
    #pragma unroll
    for (int mb = 0; mb < 2; mb++) {
      #pragma unroll
      for (int r = 0; r < 16; r++) {
        const int row = b0 + mb * 32 + (r & 3) + 8 * (r >> 2) + 4 * half;
        atomicAdd(&dst[(size_t)row * OUT_F + colb], acc[mb][r]);
      }
    }
  } else {
    float* pd = dst + (size_t)kidx * ((size_t)4096 * OUT_F);
    #pragma unroll
    for (int mb = 0; mb < 2; mb++) {
      #pragma unroll
      for (int r = 0; r < 16; r++) {
        const int row = b0 + mb * 32 + (r & 3) + 8 * (r >> 2) + 4 * half;
        pd[(size_t)row * OUT_F + colb] = acc[mb][r];
      }
    }
  }
}

// ---- split-K reduce: out = sum of 8 partial tiles ----
__global__ void kan_reduce(const float* __restrict__ part, float* __restrict__ out) {
  const size_t j = ((size_t)blockIdx.x * 256 + threadIdx.x) * 4;
  float4 a = *(const float4*)(part + j);
  #pragma unroll
  for (int s = 1; s < 8; s++) {
    float4 b = *(const float4*)(part + (size_t)s * 1048576 + j);
    a.x += b.x; a.y += b.y; a.z += b.z; a.w += b.w;
  }
  *(float4*)(out + j) = a;
}

// ---- naive fallback (only if d_ws is too small): correct, slow ----
__global__ void kan_naive(const float* __restrict__ x, const float* __restrict__ bw,
                          const float* __restrict__ sw, const float* __restrict__ sca,
                          float* __restrict__ out) {
  const int o = threadIdx.x;
  const int b = blockIdx.x;
  float accb = 0.0f, accs = 0.0f, scl = 0.0f;
  for (int i = 0; i < IN_F; i++) {
    const float xraw = x[(size_t)b * IN_F + i];
    accb += xraw * bw[(size_t)i * OUT_F + o];
    scl += fmaxf(sca[(size_t)i * OUT_F + o], 1e-7f);
    const float xc = fminf(fmaxf(xraw, -1.0f), 1.0f);
    const float xs = (xc + 1.0f) * (63.0f / (2.0f + 1e-7f));
    const float tl = xs - fminf(floorf(xs), 61.0f);
    const int kc = (int)(tl * 65.0f + 0.5f);
    const int k0 = max(0, min(kc - 8, 50));
    float e[16]; float s = 0.0f;
    #pragma unroll
    for (int j = 0; j < 16; j++) {
      float d = tl - (float)(k0 + j) * (1.0f / 65.0f);
      e[j] = __expf(-2178.0f * d * d);
      s += e[j];
    }
    const float r = __fdividef(1.0f, s + 1e-7f);
    const float* wrow = sw + ((size_t)i * OUT_F + o) * NB + k0;
    float dot = 0.0f;
    #pragma unroll
    for (int j = 0; j < 16; j++) dot += e[j] * wrow[j];
    accs += dot * r;
  }
  out[(size_t)b * OUT_F + o] = accb + accs * (scl * (1.0f / 256.0f));
}

extern "C" void kernel_launch(void* const* d_in, const int* in_sizes, int n_in,
                              void* d_out, int out_size, void* d_ws, size_t ws_size,
                              hipStream_t stream) {
  const float* x   = (const float*)d_in[0];
  const float* bw  = (const float*)d_in[1];
  const float* sw  = (const float*)d_in[2];
  const float* sca = (const float*)d_in[3];
  float* out = (float*)d_out;

  const size_t WP2_BYTES  = (size_t)IN_F * OUT_F * KP * 2;          // 10485760
  const size_t PART_BYTES = (size_t)KSPLIT * 4096 * OUT_F * 4;      // 33554432

  if (ws_size >= WP2_BYTES + PART_BYTES) {
    unsigned short* wp2 = (unsigned short*)d_ws;
    float* part = (float*)((char*)d_ws + WP2_BYTES);
    kan_pack<<<256, 256, 0, stream>>>(sw, bw, sca, wp2);
    kan_main<<<GRID_MAIN, NTHREADS, 0, stream>>>(x, wp2, part, 0);
    kan_reduce<<<1024, 256, 0, stream>>>(part, out);
  } else if (ws_size >= WP2_BYTES) {
    unsigned short* wp2 = (unsigned short*)d_ws;
    (void)hipMemsetAsync(d_out, 0, (size_t)out_size * sizeof(float), stream);
    kan_pack<<<256, 256, 0, stream>>>(sw, bw, sca, wp2);
    kan_main<<<GRID_MAIN, NTHREADS, 0, stream>>>(x, wp2, out, 1);
  } else {
    kan_naive<<<4096, 256, 0, stream>>>(x, bw, sw, sca, out);
  }
}